// Round 8
// baseline (230.960 us; speedup 1.0000x reference)
//
#include <hip/hip_runtime.h>
#include <cstdint>
#include <cstddef>

// Fused Swin-style window attention for MI355X (gfx950), round 8.
// Evidence so far: perf flat-to-negative in occupancy (21/30/41% -> 113/124/241us)
// => latency of the per-window serial chain is the limit, not wave count.
// R8: (1) cross-window register-staged pipeline (x_{w+1} HBM->regs during window w,
// cvt+LDS-write off the critical path), 1024 blocks x 4 windows, double-buffered
// bf16 x-tile, still 2 plain __syncthreads per window (no raw barriers/vmcnt);
// (2) attention S^T and PV switched from 64 mfma16_1k to 32 mfma32 by concatenating
// pack4 halves (A/B k-slot mappings agree pairwise, contraction order-agnostic);
// (3) launch_bounds(256,2): no spill risk (R4/R7 lesson).

typedef float f32x4 __attribute__((ext_vector_type(4)));
typedef __bf16 bf16x8 __attribute__((ext_vector_type(8)));
typedef unsigned short u16x8 __attribute__((ext_vector_type(8)));
typedef unsigned short u16x4 __attribute__((ext_vector_type(4)));

#define WPB 4  // windows per block

__device__ __forceinline__ unsigned short bfs(float f) {
  return __builtin_bit_cast(unsigned short, (__bf16)f);  // HW RNE cvt
}
__device__ __forceinline__ unsigned pk2n(float a, float b) {
  return (unsigned)bfs(a) | ((unsigned)bfs(b) << 16);
}
__device__ __forceinline__ u16x8 pack8(f32x4 a, f32x4 b) {
  u16x8 r;
  r[0] = bfs(a[0]); r[1] = bfs(a[1]); r[2] = bfs(a[2]); r[3] = bfs(a[3]);
  r[4] = bfs(b[0]); r[5] = bfs(b[1]); r[6] = bfs(b[2]); r[7] = bfs(b[3]);
  return r;
}
__device__ __forceinline__ f32x4 bf4up(u16x4 v) {
  f32x4 r;
  r[0] = __builtin_bit_cast(float, (unsigned)v[0] << 16);
  r[1] = __builtin_bit_cast(float, (unsigned)v[1] << 16);
  r[2] = __builtin_bit_cast(float, (unsigned)v[2] << 16);
  r[3] = __builtin_bit_cast(float, (unsigned)v[3] << 16);
  return r;
}
__device__ __forceinline__ f32x4 mfma32(u16x8 a, u16x8 b, f32x4 c) {
  return __builtin_amdgcn_mfma_f32_16x16x32_bf16(
      __builtin_bit_cast(bf16x8, a), __builtin_bit_cast(bf16x8, b), c, 0, 0, 0);
}

// ---------------- prep: weights^T -> bf16, rel-pos bias -> bf16 frag layout ----------
// ws: [0,98304)        wqkv_t bf16 [384 cols][128 k]   (Q cols scaled by log2e/sqrt(hd))
//     [98304,131072)   wproj_t bf16 [128 cols][128 k]
//     [131072,163840)  bias bf16 [h][mk][nq][lane][i]  (S^T frag layout, * log2e)
__global__ void prep_kernel(const float* __restrict__ wqkv, const float* __restrict__ wproj,
                            const float* __restrict__ btab,
                            unsigned short* __restrict__ wqkvt,
                            unsigned short* __restrict__ wprojt,
                            unsigned short* __restrict__ biasbf) {
  int t = blockIdx.x * 256 + threadIdx.x;
  if (t < 49152) {
    int c = t >> 7, k = t & 127;
    float v = wqkv[k * 384 + c];
    if (c < 128) v *= 0.25503486f;  // log2(e)/sqrt(32)
    wqkvt[t] = bfs(v);
  } else if (t < 65536) {
    int t2 = t - 49152;
    int c = t2 >> 7, k = t2 & 127;
    wprojt[t2] = bfs(wproj[k * 128 + c]);
  } else if (t < 81920) {
    int t3 = t - 65536;
    int i = t3 & 3, lane = (t3 >> 2) & 63, nq = (t3 >> 8) & 3, mk = (t3 >> 10) & 3, h = t3 >> 12;
    int key = mk * 16 + ((lane >> 4) << 2) + i;  // S^T row (C-layout)
    int q   = nq * 16 + (lane & 15);             // S^T col
    int idx = ((q >> 3) - (key >> 3) + 7) * 15 + ((q & 7) - (key & 7) + 7);
    biasbf[t3] = bfs(btab[idx * 4 + h] * 1.4426950408889634f);
  }
}

// ---------------- fused attention: WPB windows / block, pipelined stage ----------
__global__ __launch_bounds__(256, 2) void attn_kernel(
    const float* __restrict__ x, const unsigned short* __restrict__ wqkvt,
    const unsigned short* __restrict__ wprojt, const unsigned short* __restrict__ biasbf,
    const float* __restrict__ bproj, float* __restrict__ out) {
  __shared__ char lds[49152];
  char* xsA = lds;            // bf16 x tile, buffer A (swizzled [64 tok][128 c])
  char* xsB = lds + 16384;    // buffer B
  char* ao  = lds + 32768;    // bf16 attn-out tile
  const int tid = threadIdx.x;
  const int lane = tid & 63;
  const int h = tid >> 6;   // wave = head
  const int g = lane >> 4;
  const int q15 = lane & 15;
  const int rs = (q15 & 7) << 4;  // read swizzle; row%8 == q15%8 for our reads
  const size_t blkbase = (size_t)blockIdx.x * (WPB * 8192);
  const f32x4 zero4 = {0.f, 0.f, 0.f, 0.f};
  const char* wqb = (const char*)wqkvt;
  const char* wpb = (const char*)wprojt;
  const u16x4* bbp = (const u16x4*)biasbf;

  f32x4 bv[2];
  bv[0] = *(const f32x4*)(bproj + h * 32 + g * 4);
  bv[1] = *(const f32x4*)(bproj + h * 32 + 16 + g * 4);

  // ---- prologue: stage window 0 into xsA; keep window 1 f32 in regs ----
  f32x4 xr[8];
  {
    const float* xp0 = x + blkbase + tid * 8;
    f32x4 x0[8];
#pragma unroll
    for (int u = 0; u < 4; ++u) {
      x0[2 * u]     = *(const f32x4*)(xp0 + u * 2048);
      x0[2 * u + 1] = *(const f32x4*)(xp0 + u * 2048 + 4);
    }
#pragma unroll
    for (int u = 0; u < 4; ++u) {
      xr[2 * u]     = *(const f32x4*)(xp0 + 8192 + u * 2048);
      xr[2 * u + 1] = *(const f32x4*)(xp0 + 8192 + u * 2048 + 4);
    }
#pragma unroll
    for (int u = 0; u < 4; ++u) {
      int row = u * 16 + (tid >> 4);
      int byte = row * 256 + (((tid & 15) * 16) ^ ((row & 7) << 4));
      uint4 p;
      p.x = pk2n(x0[2 * u][0], x0[2 * u][1]);
      p.y = pk2n(x0[2 * u][2], x0[2 * u][3]);
      p.z = pk2n(x0[2 * u + 1][0], x0[2 * u + 1][1]);
      p.w = pk2n(x0[2 * u + 1][2], x0[2 * u + 1][3]);
      *(uint4*)(xsA + byte) = p;
    }
  }
  __syncthreads();  // x_0 tile visible

#pragma unroll 1
  for (int w = 0; w < WPB; ++w) {
    char* xsb = (w & 1) ? xsB : xsA;   // current window's tile
    char* xsn = (w & 1) ? xsA : xsB;   // next window's tile

    // ---- QK pass: Q^T, K^T = Wqk^T . x^T ----
    f32x4 qt[2][4], kt[2][4];
#pragma unroll
    for (int m = 0; m < 2; ++m)
#pragma unroll
      for (int t = 0; t < 4; ++t) { qt[m][t] = zero4; kt[m][t] = zero4; }
#pragma unroll
    for (int ks = 0; ks < 4; ++ks) {
      u16x8 xb[4];
#pragma unroll
      for (int t = 0; t < 4; ++t)
        xb[t] = *(const u16x8*)(xsb + (t * 16 + q15) * 256 + ((ks * 64 + g * 16) ^ rs));
      const int kb = ks * 64 + g * 16;
      u16x8 wq[2], wk[2];
#pragma unroll
      for (int m = 0; m < 2; ++m) {
        int col = h * 32 + m * 16 + q15;
        wq[m] = *(const u16x8*)(wqb + (size_t)col * 256 + kb);
        wk[m] = *(const u16x8*)(wqb + (size_t)(col + 128) * 256 + kb);
      }
#pragma unroll
      for (int m = 0; m < 2; ++m)
#pragma unroll
        for (int t = 0; t < 4; ++t) {
          qt[m][t] = mfma32(wq[m], xb[t], qt[m][t]);  // [c][tok]
          kt[m][t] = mfma32(wk[m], xb[t], kt[m][t]);
        }
    }
    // pack to u16x8 k=32 fragments (halves agree pairwise on k-slot mapping)
    u16x8 qp8[4], kp8[4];
#pragma unroll
    for (int t = 0; t < 4; ++t) {
      qp8[t] = pack8(qt[0][t], qt[1][t]);
      kp8[t] = pack8(kt[0][t], kt[1][t]);
    }

    // ---- S^T = K.Q^T + bias: one mfma32 per 16x16 tile ----
    f32x4 st[4][4];
#pragma unroll
    for (int mk = 0; mk < 4; ++mk)
#pragma unroll
      for (int nq = 0; nq < 4; ++nq)
        st[mk][nq] = bf4up(bbp[((h * 4 + mk) * 4 + nq) * 64 + lane]);
#pragma unroll
    for (int mk = 0; mk < 4; ++mk)
#pragma unroll
      for (int nq = 0; nq < 4; ++nq)
        st[mk][nq] = mfma32(kp8[mk], qp8[nq], st[mk][nq]);

    // ---- softmax over keys (logits pre-scaled by log2e; no max-subtract) ----
    float rc[4];
#pragma unroll
    for (int nq = 0; nq < 4; ++nq) {
      float s = 0.f;
#pragma unroll
      for (int mk = 0; mk < 4; ++mk)
#pragma unroll
        for (int i = 0; i < 4; ++i) {
          float e = exp2f(st[mk][nq][i]);
          st[mk][nq][i] = e;
          s += e;
        }
      s += __shfl_xor(s, 16);
      s += __shfl_xor(s, 32);
      rc[nq] = __builtin_amdgcn_rcpf(s);
    }
    u16x8 bp8[2][4];
#pragma unroll
    for (int s2 = 0; s2 < 2; ++s2)
#pragma unroll
      for (int nq = 0; nq < 4; ++nq)
        bp8[s2][nq] = pack8(st[2 * s2][nq], st[2 * s2 + 1][nq]);

    // ---- V pass: V = x . Wv ----
    f32x4 vv[4][2];
#pragma unroll
    for (int t = 0; t < 4; ++t) { vv[t][0] = zero4; vv[t][1] = zero4; }
#pragma unroll
    for (int ks = 0; ks < 4; ++ks) {
      u16x8 xb[4];
#pragma unroll
      for (int t = 0; t < 4; ++t)
        xb[t] = *(const u16x8*)(xsb + (t * 16 + q15) * 256 + ((ks * 64 + g * 16) ^ rs));
      const int kb = ks * 64 + g * 16;
      u16x8 wv[2];
#pragma unroll
      for (int n = 0; n < 2; ++n)
        wv[n] = *(const u16x8*)(wqb + (size_t)(h * 32 + n * 16 + q15 + 256) * 256 + kb);
#pragma unroll
      for (int t = 0; t < 4; ++t)
#pragma unroll
        for (int n = 0; n < 2; ++n)
          vv[t][n] = mfma32(xb[t], wv[n], vv[t][n]);  // [tok][d]
    }
    u16x8 va8[2][2];
#pragma unroll
    for (int s2 = 0; s2 < 2; ++s2)
#pragma unroll
      for (int n = 0; n < 2; ++n)
        va8[s2][n] = pack8(vv[2 * s2][n], vv[2 * s2 + 1][n]);

    // ---- PV: out^T += V^T . P^T (k-slot token maps agree on both operands) ----
    f32x4 ot[2][4];
#pragma unroll
    for (int md = 0; md < 2; ++md)
#pragma unroll
      for (int nq = 0; nq < 4; ++nq) ot[md][nq] = zero4;
#pragma unroll
    for (int s2 = 0; s2 < 2; ++s2)
#pragma unroll
      for (int md = 0; md < 2; ++md)
#pragma unroll
        for (int nq = 0; nq < 4; ++nq)
          ot[md][nq] = mfma32(va8[s2][md], bp8[s2][nq], ot[md][nq]);

    // ---- issue proj weight loads (consumed after the barrier) ----
    u16x8 wp[4][2];
#pragma unroll
    for (int ks = 0; ks < 4; ++ks)
#pragma unroll
      for (int n = 0; n < 2; ++n)
        wp[ks][n] = *(const u16x8*)(wpb + (size_t)(h * 32 + n * 16 + q15) * 256 + ks * 64 + g * 16);

    // ---- stage attn-out bf16 into ao ----
#pragma unroll
    for (int md = 0; md < 2; ++md)
#pragma unroll
      for (int nq = 0; nq < 4; ++nq) {
        int tok = nq * 16 + q15;
        int cb = (h * 64 + md * 32 + g * 8) ^ rs;  // tok&7 == q15&7
        uint2 w2;
        w2.x = pk2n(ot[md][nq][0] * rc[nq], ot[md][nq][1] * rc[nq]);
        w2.y = pk2n(ot[md][nq][2] * rc[nq], ot[md][nq][3] * rc[nq]);
        *(uint2*)(ao + tok * 256 + cb) = w2;
      }

    // ---- pipelined stage: write x_{w+1} tile; issue x_{w+2} loads ----
    if (w < WPB - 1) {
#pragma unroll
      for (int u = 0; u < 4; ++u) {
        int row = u * 16 + (tid >> 4);
        int byte = row * 256 + (((tid & 15) * 16) ^ ((row & 7) << 4));
        uint4 p;
        p.x = pk2n(xr[2 * u][0], xr[2 * u][1]);
        p.y = pk2n(xr[2 * u][2], xr[2 * u][3]);
        p.z = pk2n(xr[2 * u + 1][0], xr[2 * u + 1][1]);
        p.w = pk2n(xr[2 * u + 1][2], xr[2 * u + 1][3]);
        *(uint4*)(xsn + byte) = p;
      }
    }
    if (w < WPB - 2) {
      const float* xp = x + blkbase + (size_t)(w + 2) * 8192 + tid * 8;
#pragma unroll
      for (int u = 0; u < 4; ++u) {
        xr[2 * u]     = *(const f32x4*)(xp + u * 2048);
        xr[2 * u + 1] = *(const f32x4*)(xp + u * 2048 + 4);
      }
    }
    __syncthreads();  // ao ready + next x tile ready

    // ---- proj GEMM (transposed): po = Wp^T . ao^T -> [ch][tok], f32x4 stores ----
    f32x4 po[2][4];
#pragma unroll
    for (int n = 0; n < 2; ++n)
#pragma unroll
      for (int t = 0; t < 4; ++t) po[n][t] = zero4;
#pragma unroll
    for (int ks = 0; ks < 4; ++ks) {
      u16x8 axb[4];
#pragma unroll
      for (int t = 0; t < 4; ++t)
        axb[t] = *(const u16x8*)(ao + (t * 16 + q15) * 256 + ((ks * 64 + g * 16) ^ rs));
#pragma unroll
      for (int n = 0; n < 2; ++n)
#pragma unroll
        for (int t = 0; t < 4; ++t)
          po[n][t] = mfma32(wp[ks][n], axb[t], po[n][t]);  // [ch][tok]
    }
    float* op = out + blkbase + (size_t)w * 8192;
#pragma unroll
    for (int n = 0; n < 2; ++n)
#pragma unroll
      for (int t = 0; t < 4; ++t) {
        f32x4 vs = po[n][t] + bv[n];
        *(f32x4*)(op + (size_t)(t * 16 + q15) * 128 + h * 32 + n * 16 + g * 4) = vs;
      }
    __syncthreads();  // ao reads done before next window overwrites
  }
}

extern "C" void kernel_launch(void* const* d_in, const int* in_sizes, int n_in,
                              void* d_out, int out_size, void* d_ws, size_t ws_size,
                              hipStream_t stream) {
  const float* x     = (const float*)d_in[0];
  const float* wqkv  = (const float*)d_in[1];
  const float* wproj = (const float*)d_in[2];
  const float* bproj = (const float*)d_in[3];
  const float* btab  = (const float*)d_in[4];
  char* ws = (char*)d_ws;
  unsigned short* wqkvt  = (unsigned short*)ws;             // 98304 B
  unsigned short* wprojt = (unsigned short*)(ws + 98304);   // 32768 B
  unsigned short* biasbf = (unsigned short*)(ws + 131072);  // 32768 B

  prep_kernel<<<320, 256, 0, stream>>>(wqkv, wproj, btab, wqkvt, wprojt, biasbf);
  attn_kernel<<<4096 / WPB, 256, 0, stream>>>(x, wqkvt, wprojt, biasbf, bproj, (float*)d_out);
}

// Round 10
// 224.049 us; speedup vs baseline: 1.0308x; 1.0308x over previous
//
#include <hip/hip_runtime.h>
#include <cstdint>
#include <cstddef>

// Fused Swin-style window attention for MI355X (gfx950), round 9 (resubmit; the
// R9 bench died on an unresponsive container before producing any signal).
// Evidence: R1/R5 simple structure = 110-113us (no spills, FETCH 67/WRITE 131 MB);
// occupancy does NOT correlate with perf; every reg-pressure overrun spills and loses.
// R9 = R5 split-pass structure + WPB=4 cross-window prefetch with SHORT register
// live range (xr loaded after the low-pressure V-pass, consumed before the same
// window's barrier) + R8's validated mfma32 concat attention (32 vs 64 matrix ops)
// + bias fragments hoisted to registers. Two plain __syncthreads per window.

typedef float f32x4 __attribute__((ext_vector_type(4)));
typedef __bf16 bf16x8 __attribute__((ext_vector_type(8)));
typedef unsigned short u16x8 __attribute__((ext_vector_type(8)));
typedef unsigned short u16x4 __attribute__((ext_vector_type(4)));

#define WPB 4  // windows per block

__device__ __forceinline__ unsigned short bfs(float f) {
  return __builtin_bit_cast(unsigned short, (__bf16)f);  // HW RNE cvt
}
__device__ __forceinline__ unsigned pk2n(float a, float b) {
  return (unsigned)bfs(a) | ((unsigned)bfs(b) << 16);
}
__device__ __forceinline__ u16x8 pack8(f32x4 a, f32x4 b) {
  u16x8 r;
  r[0] = bfs(a[0]); r[1] = bfs(a[1]); r[2] = bfs(a[2]); r[3] = bfs(a[3]);
  r[4] = bfs(b[0]); r[5] = bfs(b[1]); r[6] = bfs(b[2]); r[7] = bfs(b[3]);
  return r;
}
__device__ __forceinline__ f32x4 bf4up(u16x4 v) {
  f32x4 r;
  r[0] = __builtin_bit_cast(float, (unsigned)v[0] << 16);
  r[1] = __builtin_bit_cast(float, (unsigned)v[1] << 16);
  r[2] = __builtin_bit_cast(float, (unsigned)v[2] << 16);
  r[3] = __builtin_bit_cast(float, (unsigned)v[3] << 16);
  return r;
}
__device__ __forceinline__ f32x4 mfma32(u16x8 a, u16x8 b, f32x4 c) {
  return __builtin_amdgcn_mfma_f32_16x16x32_bf16(
      __builtin_bit_cast(bf16x8, a), __builtin_bit_cast(bf16x8, b), c, 0, 0, 0);
}

// ---------------- prep: weights^T -> bf16, rel-pos bias -> bf16 frag layout ----------
// ws: [0,98304)        wqkv_t bf16 [384 cols][128 k]   (Q cols scaled by log2e/sqrt(hd))
//     [98304,131072)   wproj_t bf16 [128 cols][128 k]
//     [131072,163840)  bias bf16 [h][mk][nq][lane][i]  (S^T frag layout, * log2e)
__global__ void prep_kernel(const float* __restrict__ wqkv, const float* __restrict__ wproj,
                            const float* __restrict__ btab,
                            unsigned short* __restrict__ wqkvt,
                            unsigned short* __restrict__ wprojt,
                            unsigned short* __restrict__ biasbf) {
  int t = blockIdx.x * 256 + threadIdx.x;
  if (t < 49152) {
    int c = t >> 7, k = t & 127;
    float v = wqkv[k * 384 + c];
    if (c < 128) v *= 0.25503486f;  // log2(e)/sqrt(32)
    wqkvt[t] = bfs(v);
  } else if (t < 65536) {
    int t2 = t - 49152;
    int c = t2 >> 7, k = t2 & 127;
    wprojt[t2] = bfs(wproj[k * 128 + c]);
  } else if (t < 81920) {
    int t3 = t - 65536;
    int i = t3 & 3, lane = (t3 >> 2) & 63, nq = (t3 >> 8) & 3, mk = (t3 >> 10) & 3, h = t3 >> 12;
    int key = mk * 16 + ((lane >> 4) << 2) + i;  // S^T row (C-layout)
    int q   = nq * 16 + (lane & 15);             // S^T col
    int idx = ((q >> 3) - (key >> 3) + 7) * 15 + ((q & 7) - (key & 7) + 7);
    biasbf[t3] = bfs(btab[idx * 4 + h] * 1.4426950408889634f);
  }
}

// ---------------- fused attention: WPB windows / block, short-lived prefetch ----------
__global__ __launch_bounds__(256, 2) void attn_kernel(
    const float* __restrict__ x, const unsigned short* __restrict__ wqkvt,
    const unsigned short* __restrict__ wprojt, const unsigned short* __restrict__ biasbf,
    const float* __restrict__ bproj, float* __restrict__ out) {
  __shared__ char lds[49152];
  char* xsA = lds;            // bf16 x tile, buffer A (swizzled [64 tok][128 c])
  char* xsB = lds + 16384;    // buffer B
  char* ao  = lds + 32768;    // bf16 attn-out tile
  const int tid = threadIdx.x;
  const int lane = tid & 63;
  const int h = tid >> 6;   // wave = head
  const int g = lane >> 4;
  const int q15 = lane & 15;
  const int rs = (q15 & 7) << 4;  // read swizzle; row%8 == q15%8 for our reads
  const size_t blkbase = (size_t)blockIdx.x * (WPB * 8192);
  const f32x4 zero4 = {0.f, 0.f, 0.f, 0.f};
  const char* wqb = (const char*)wqkvt;
  const char* wpb = (const char*)wprojt;

  // ---- per-block-constant register state ----
  u16x4 bias[4][4];
#pragma unroll
  for (int mk = 0; mk < 4; ++mk)
#pragma unroll
    for (int nq = 0; nq < 4; ++nq)
      bias[mk][nq] = ((const u16x4*)biasbf)[((h * 4 + mk) * 4 + nq) * 64 + lane];
  f32x4 bv[2];
  bv[0] = *(const f32x4*)(bproj + h * 32 + g * 4);
  bv[1] = *(const f32x4*)(bproj + h * 32 + 16 + g * 4);

  // ---- prologue: stage window 0 into xsA ----
  {
    const float* xp0 = x + blkbase + tid * 8;
#pragma unroll
    for (int u = 0; u < 4; ++u) {
      f32x4 a = *(const f32x4*)(xp0 + u * 2048);
      f32x4 b = *(const f32x4*)(xp0 + u * 2048 + 4);
      int row = u * 16 + (tid >> 4);
      int byte = row * 256 + (((tid & 15) * 16) ^ ((row & 7) << 4));
      uint4 p;
      p.x = pk2n(a[0], a[1]); p.y = pk2n(a[2], a[3]);
      p.z = pk2n(b[0], b[1]); p.w = pk2n(b[2], b[3]);
      *(uint4*)(xsA + byte) = p;
    }
  }
  __syncthreads();  // x_0 tile visible

#pragma unroll 1
  for (int w = 0; w < WPB; ++w) {
    char* xsb = (w & 1) ? xsB : xsA;   // current window's tile
    char* xsn = (w & 1) ? xsA : xsB;   // next window's tile

    // ---- sub-pass A: Q^T, K^T = Wqk^T . x^T ----
    f32x4 qt[2][4], kt[2][4];
#pragma unroll
    for (int m = 0; m < 2; ++m)
#pragma unroll
      for (int t = 0; t < 4; ++t) { qt[m][t] = zero4; kt[m][t] = zero4; }
#pragma unroll
    for (int ks = 0; ks < 4; ++ks) {
      u16x8 xb[4];
#pragma unroll
      for (int t = 0; t < 4; ++t)
        xb[t] = *(const u16x8*)(xsb + (t * 16 + q15) * 256 + ((ks * 64 + g * 16) ^ rs));
      const int kb = ks * 64 + g * 16;
      u16x8 wq[2], wk[2];
#pragma unroll
      for (int m = 0; m < 2; ++m) {
        int col = h * 32 + m * 16 + q15;
        wq[m] = *(const u16x8*)(wqb + (size_t)col * 256 + kb);
        wk[m] = *(const u16x8*)(wqb + (size_t)(col + 128) * 256 + kb);
      }
#pragma unroll
      for (int m = 0; m < 2; ++m)
#pragma unroll
        for (int t = 0; t < 4; ++t) {
          qt[m][t] = mfma32(wq[m], xb[t], qt[m][t]);  // [c][tok]
          kt[m][t] = mfma32(wk[m], xb[t], kt[m][t]);
        }
    }
    u16x8 qp8[4], kp8[4];
#pragma unroll
    for (int t = 0; t < 4; ++t) {
      qp8[t] = pack8(qt[0][t], qt[1][t]);  // k=32 concat frags (validated R8)
      kp8[t] = pack8(kt[0][t], kt[1][t]);
    }

    // ---- sub-pass B: V = x . Wv (re-read xs; QK accs freed) ----
    f32x4 vv[4][2];
#pragma unroll
    for (int t = 0; t < 4; ++t) { vv[t][0] = zero4; vv[t][1] = zero4; }
#pragma unroll
    for (int ks = 0; ks < 4; ++ks) {
      u16x8 xb[4];
#pragma unroll
      for (int t = 0; t < 4; ++t)
        xb[t] = *(const u16x8*)(xsb + (t * 16 + q15) * 256 + ((ks * 64 + g * 16) ^ rs));
      const int kb = ks * 64 + g * 16;
      u16x8 wv[2];
#pragma unroll
      for (int n = 0; n < 2; ++n)
        wv[n] = *(const u16x8*)(wqb + (size_t)(h * 32 + n * 16 + q15 + 256) * 256 + kb);
#pragma unroll
      for (int t = 0; t < 4; ++t)
#pragma unroll
        for (int n = 0; n < 2; ++n)
          vv[t][n] = mfma32(xb[t], wv[n], vv[t][n]);  // [tok][d]
    }

    // ---- issue x_{w+1} loads NOW (low-pressure point); consumed before barrier B1 ----
    f32x4 xr[8];
    if (w < WPB - 1) {
      const float* xp = x + blkbase + (size_t)(w + 1) * 8192 + tid * 8;
#pragma unroll
      for (int u = 0; u < 4; ++u) {
        xr[2 * u]     = *(const f32x4*)(xp + u * 2048);
        xr[2 * u + 1] = *(const f32x4*)(xp + u * 2048 + 4);
      }
    }
    __builtin_amdgcn_sched_barrier(0);  // keep loads issued here (don't sink below)

    u16x8 va8[2][2];
#pragma unroll
    for (int s2 = 0; s2 < 2; ++s2)
#pragma unroll
      for (int n = 0; n < 2; ++n)
        va8[s2][n] = pack8(vv[2 * s2][n], vv[2 * s2 + 1][n]);

    // ---- S^T = K.Q^T + bias: one mfma32 per 16x16 tile ----
    f32x4 st[4][4];
#pragma unroll
    for (int mk = 0; mk < 4; ++mk)
#pragma unroll
      for (int nq = 0; nq < 4; ++nq)
        st[mk][nq] = bf4up(bias[mk][nq]);
#pragma unroll
    for (int mk = 0; mk < 4; ++mk)
#pragma unroll
      for (int nq = 0; nq < 4; ++nq)
        st[mk][nq] = mfma32(kp8[mk], qp8[nq], st[mk][nq]);

    // ---- softmax over keys (logits pre-scaled by log2e; no max-subtract) ----
    float rc[4];
#pragma unroll
    for (int nq = 0; nq < 4; ++nq) {
      float s = 0.f;
#pragma unroll
      for (int mk = 0; mk < 4; ++mk)
#pragma unroll
        for (int i = 0; i < 4; ++i) {
          float e = exp2f(st[mk][nq][i]);
          st[mk][nq][i] = e;
          s += e;
        }
      s += __shfl_xor(s, 16);
      s += __shfl_xor(s, 32);
      rc[nq] = __builtin_amdgcn_rcpf(s);
    }
    u16x8 bp8[2][4];
#pragma unroll
    for (int s2 = 0; s2 < 2; ++s2)
#pragma unroll
      for (int nq = 0; nq < 4; ++nq)
        bp8[s2][nq] = pack8(st[2 * s2][nq], st[2 * s2 + 1][nq]);

    // ---- PV: out^T += V^T . P^T ----
    f32x4 ot[2][4];
#pragma unroll
    for (int md = 0; md < 2; ++md)
#pragma unroll
      for (int nq = 0; nq < 4; ++nq) ot[md][nq] = zero4;
#pragma unroll
    for (int s2 = 0; s2 < 2; ++s2)
#pragma unroll
      for (int md = 0; md < 2; ++md)
#pragma unroll
        for (int nq = 0; nq < 4; ++nq)
          ot[md][nq] = mfma32(va8[s2][md], bp8[s2][nq], ot[md][nq]);

    // ---- stage attn-out bf16 into ao ----
#pragma unroll
    for (int md = 0; md < 2; ++md)
#pragma unroll
      for (int nq = 0; nq < 4; ++nq) {
        int tok = nq * 16 + q15;
        int cb = (h * 64 + md * 32 + g * 8) ^ rs;  // tok&7 == q15&7
        uint2 w2;
        w2.x = pk2n(ot[md][nq][0] * rc[nq], ot[md][nq][1] * rc[nq]);
        w2.y = pk2n(ot[md][nq][2] * rc[nq], ot[md][nq][3] * rc[nq]);
        *(uint2*)(ao + tok * 256 + cb) = w2;
      }

    // ---- convert + write x_{w+1} tile (xr freed here, before the barrier) ----
    if (w < WPB - 1) {
#pragma unroll
      for (int u = 0; u < 4; ++u) {
        int row = u * 16 + (tid >> 4);
        int byte = row * 256 + (((tid & 15) * 16) ^ ((row & 7) << 4));
        uint4 p;
        p.x = pk2n(xr[2 * u][0], xr[2 * u][1]);
        p.y = pk2n(xr[2 * u][2], xr[2 * u][3]);
        p.z = pk2n(xr[2 * u + 1][0], xr[2 * u + 1][1]);
        p.w = pk2n(xr[2 * u + 1][2], xr[2 * u + 1][3]);
        *(uint4*)(xsn + byte) = p;
      }
    }

    // ---- proj weight loads (L2-hot), consumed after the barrier ----
    u16x8 wp[4][2];
#pragma unroll
    for (int ks = 0; ks < 4; ++ks)
#pragma unroll
      for (int n = 0; n < 2; ++n)
        wp[ks][n] = *(const u16x8*)(wpb + (size_t)(h * 32 + n * 16 + q15) * 256 + ks * 64 + g * 16);
    __syncthreads();  // B1: ao ready + next x tile ready

    // ---- proj GEMM (transposed): po = Wp^T . ao^T -> [ch][tok], f32x4 stores ----
    f32x4 po[2][4];
#pragma unroll
    for (int n = 0; n < 2; ++n)
#pragma unroll
      for (int t = 0; t < 4; ++t) po[n][t] = zero4;
#pragma unroll
    for (int ks = 0; ks < 4; ++ks) {
      u16x8 axb[4];
#pragma unroll
      for (int t = 0; t < 4; ++t)
        axb[t] = *(const u16x8*)(ao + (t * 16 + q15) * 256 + ((ks * 64 + g * 16) ^ rs));
#pragma unroll
      for (int n = 0; n < 2; ++n)
#pragma unroll
        for (int t = 0; t < 4; ++t)
          po[n][t] = mfma32(wp[ks][n], axb[t], po[n][t]);  // [ch][tok]
    }
    float* op = out + blkbase + (size_t)w * 8192;
#pragma unroll
    for (int n = 0; n < 2; ++n)
#pragma unroll
      for (int t = 0; t < 4; ++t) {
        f32x4 vs = po[n][t] + bv[n];
        *(f32x4*)(op + (size_t)(t * 16 + q15) * 128 + h * 32 + n * 16 + g * 4) = vs;
      }
    if (w < WPB - 1) __syncthreads();  // B2: ao consumed; next window may overwrite
  }
}

extern "C" void kernel_launch(void* const* d_in, const int* in_sizes, int n_in,
                              void* d_out, int out_size, void* d_ws, size_t ws_size,
                              hipStream_t stream) {
  const float* x     = (const float*)d_in[0];
  const float* wqkv  = (const float*)d_in[1];
  const float* wproj = (const float*)d_in[2];
  const float* bproj = (const float*)d_in[3];
  const float* btab  = (const float*)d_in[4];
  char* ws = (char*)d_ws;
  unsigned short* wqkvt  = (unsigned short*)ws;             // 98304 B
  unsigned short* wprojt = (unsigned short*)(ws + 98304);   // 32768 B
  unsigned short* biasbf = (unsigned short*)(ws + 131072);  // 32768 B

  prep_kernel<<<320, 256, 0, stream>>>(wqkv, wproj, btab, wqkvt, wprojt, biasbf);
  attn_kernel<<<4096 / WPB, 256, 0, stream>>>(x, wqkvt, wprojt, biasbf, bproj, (float*)d_out);
}

// Round 14
// 136.678 us; speedup vs baseline: 1.6898x; 1.6392x over previous
//
#include <hip/hip_runtime.h>
#include <cstdint>
#include <cstddef>

// Fused Swin-style window attention for MI355X (gfx950), round 13 (resubmit;
// the R13 bench died on an unresponsive container before producing any signal).
// R12 lesson: deferred softmax normalization past the proj GEMM is WRONG --
// proj mixes channels of all 4 heads, each with a different denominator.
// Normalize per-(head,query) BEFORE staging ao (as R6 did). Everything else
// from R11 retained: mfma32 concat attention (32 matrix ops), f32 bias loaded
// straight into S accumulators, wp/bv after the barrier, launch_bounds(256,3).

typedef float f32x4 __attribute__((ext_vector_type(4)));
typedef __bf16 bf16x8 __attribute__((ext_vector_type(8)));
typedef unsigned short u16x8 __attribute__((ext_vector_type(8)));

__device__ __forceinline__ unsigned short bfs(float f) {
  return __builtin_bit_cast(unsigned short, (__bf16)f);  // HW RNE cvt
}
__device__ __forceinline__ unsigned pk2n(float a, float b) {
  return (unsigned)bfs(a) | ((unsigned)bfs(b) << 16);
}
__device__ __forceinline__ u16x8 pack8(f32x4 a, f32x4 b) {
  u16x8 r;
  r[0] = bfs(a[0]); r[1] = bfs(a[1]); r[2] = bfs(a[2]); r[3] = bfs(a[3]);
  r[4] = bfs(b[0]); r[5] = bfs(b[1]); r[6] = bfs(b[2]); r[7] = bfs(b[3]);
  return r;
}
__device__ __forceinline__ f32x4 mfma32(u16x8 a, u16x8 b, f32x4 c) {
  return __builtin_amdgcn_mfma_f32_16x16x32_bf16(
      __builtin_bit_cast(bf16x8, a), __builtin_bit_cast(bf16x8, b), c, 0, 0, 0);
}

// ---------------- prep: weights^T -> bf16, rel-pos bias -> f32 frag layout ----------
// ws: [0,98304)        wqkv_t bf16 [384 cols][128 k]   (Q cols scaled by log2e/sqrt(hd))
//     [98304,131072)   wproj_t bf16 [128 cols][128 k]
//     [131072,196608)  bias f32 [h][mk][nq][lane][i]   (S^T frag layout, * log2e)
__global__ void prep_kernel(const float* __restrict__ wqkv, const float* __restrict__ wproj,
                            const float* __restrict__ btab,
                            unsigned short* __restrict__ wqkvt,
                            unsigned short* __restrict__ wprojt,
                            float* __restrict__ biasf) {
  int t = blockIdx.x * 256 + threadIdx.x;
  if (t < 49152) {
    int c = t >> 7, k = t & 127;
    float v = wqkv[k * 384 + c];
    if (c < 128) v *= 0.25503486f;  // log2(e)/sqrt(32)
    wqkvt[t] = bfs(v);
  } else if (t < 65536) {
    int t2 = t - 49152;
    int c = t2 >> 7, k = t2 & 127;
    wprojt[t2] = bfs(wproj[k * 128 + c]);
  } else if (t < 81920) {
    int t3 = t - 65536;
    int i = t3 & 3, lane = (t3 >> 2) & 63, nq = (t3 >> 8) & 3, mk = (t3 >> 10) & 3, h = t3 >> 12;
    int key = mk * 16 + ((lane >> 4) << 2) + i;  // S^T row (C-layout)
    int q   = nq * 16 + (lane & 15);             // S^T col
    int idx = ((q >> 3) - (key >> 3) + 7) * 15 + ((q & 7) - (key & 7) + 7);
    biasf[t3] = btab[idx * 4 + h] * 1.4426950408889634f;
  }
}

// ---------------- fused attention: 1 window / block ----------------
__global__ __launch_bounds__(256, 3) void attn_kernel(
    const float* __restrict__ x, const unsigned short* __restrict__ wqkvt,
    const unsigned short* __restrict__ wprojt, const float* __restrict__ biasf,
    const float* __restrict__ bproj, float* __restrict__ out) {
  __shared__ char lds[32768];
  char* xs = lds;           // bf16 x tile [64 tok][128 c], byte-XOR swizzled
  char* ao = lds + 16384;   // bf16 attn-out tile, same swizzle
  const int tid = threadIdx.x;
  const int lane = tid & 63;
  const int h = tid >> 6;   // wave = head
  const int g = lane >> 4;
  const int q15 = lane & 15;
  const int rs = (q15 & 7) << 4;  // read swizzle; row%8 == q15%8 for our reads
  const size_t wbase = (size_t)blockIdx.x * 8192;
  const f32x4 zero4 = {0.f, 0.f, 0.f, 0.f};
  const char* wqb = (const char*)wqkvt;
  const char* wpb = (const char*)wprojt;

  // ---- stage x: f32 -> bf16 (native cvt_pk), swizzled ----
  {
    const int row = tid >> 2;
    const int cb = (tid & 3) * 32;
    const float* xp = x + wbase + row * 128 + cb;
#pragma unroll
    for (int u = 0; u < 4; ++u) {
      f32x4 a = *(const f32x4*)(xp + u * 8);
      f32x4 b = *(const f32x4*)(xp + u * 8 + 4);
      uint4 p;
      p.x = pk2n(a[0], a[1]); p.y = pk2n(a[2], a[3]);
      p.z = pk2n(b[0], b[1]); p.w = pk2n(b[2], b[3]);
      int byte = row * 256 + (((cb * 2) + u * 16) ^ ((row & 7) << 4));
      *(uint4*)(xs + byte) = p;
    }
  }
  __syncthreads();  // A: x tile visible

  // ---- sub-pass A: Q^T, K^T = Wqk^T . x^T ----
  f32x4 qt[2][4], kt[2][4];
#pragma unroll
  for (int m = 0; m < 2; ++m)
#pragma unroll
    for (int t = 0; t < 4; ++t) { qt[m][t] = zero4; kt[m][t] = zero4; }
#pragma unroll
  for (int ks = 0; ks < 4; ++ks) {
    u16x8 xb[4];
#pragma unroll
    for (int t = 0; t < 4; ++t)
      xb[t] = *(const u16x8*)(xs + (t * 16 + q15) * 256 + ((ks * 64 + g * 16) ^ rs));
    const int kb = ks * 64 + g * 16;
    u16x8 wq[2], wk[2];
#pragma unroll
    for (int m = 0; m < 2; ++m) {
      int col = h * 32 + m * 16 + q15;
      wq[m] = *(const u16x8*)(wqb + (size_t)col * 256 + kb);
      wk[m] = *(const u16x8*)(wqb + (size_t)(col + 128) * 256 + kb);
    }
#pragma unroll
    for (int m = 0; m < 2; ++m)
#pragma unroll
      for (int t = 0; t < 4; ++t) {
        qt[m][t] = mfma32(wq[m], xb[t], qt[m][t]);  // [c][tok]
        kt[m][t] = mfma32(wk[m], xb[t], kt[m][t]);
      }
  }
  u16x8 qp8[4], kp8[4];
#pragma unroll
  for (int t = 0; t < 4; ++t) {
    qp8[t] = pack8(qt[0][t], qt[1][t]);  // k=32 concat frags (validated R8)
    kp8[t] = pack8(kt[0][t], kt[1][t]);
  }

  // ---- sub-pass B: V = x . Wv (re-read xs; QK accs freed) ----
  f32x4 vv[4][2];
#pragma unroll
  for (int t = 0; t < 4; ++t) { vv[t][0] = zero4; vv[t][1] = zero4; }
#pragma unroll
  for (int ks = 0; ks < 4; ++ks) {
    u16x8 xb[4];
#pragma unroll
    for (int t = 0; t < 4; ++t)
      xb[t] = *(const u16x8*)(xs + (t * 16 + q15) * 256 + ((ks * 64 + g * 16) ^ rs));
    const int kb = ks * 64 + g * 16;
    u16x8 wv[2];
#pragma unroll
    for (int n = 0; n < 2; ++n)
      wv[n] = *(const u16x8*)(wqb + (size_t)(h * 32 + n * 16 + q15 + 256) * 256 + kb);
#pragma unroll
    for (int t = 0; t < 4; ++t)
#pragma unroll
      for (int n = 0; n < 2; ++n)
        vv[t][n] = mfma32(xb[t], wv[n], vv[t][n]);  // [tok][d]
  }
  u16x8 va8[2][2];
#pragma unroll
  for (int s2 = 0; s2 < 2; ++s2)
#pragma unroll
    for (int n = 0; n < 2; ++n)
      va8[s2][n] = pack8(vv[2 * s2][n], vv[2 * s2 + 1][n]);

  // ---- S^T = K.Q^T + bias (f32 bias loaded straight into accumulators, L2-hot) ----
  f32x4 st[4][4];
  const f32x4* bst = (const f32x4*)biasf;
#pragma unroll
  for (int mk = 0; mk < 4; ++mk)
#pragma unroll
    for (int nq = 0; nq < 4; ++nq)
      st[mk][nq] = bst[((h * 4 + mk) * 4 + nq) * 64 + lane];
#pragma unroll
  for (int mk = 0; mk < 4; ++mk)
#pragma unroll
    for (int nq = 0; nq < 4; ++nq)
      st[mk][nq] = mfma32(kp8[mk], qp8[nq], st[mk][nq]);

  // ---- softmax (logits pre-scaled by log2e; no max-subtract needed) ----
  float rc[4];
#pragma unroll
  for (int nq = 0; nq < 4; ++nq) {
    float s = 0.f;
#pragma unroll
    for (int mk = 0; mk < 4; ++mk)
#pragma unroll
      for (int i = 0; i < 4; ++i) {
        float e = exp2f(st[mk][nq][i]);
        st[mk][nq][i] = e;
        s += e;
      }
    s += __shfl_xor(s, 16);
    s += __shfl_xor(s, 32);
    rc[nq] = __builtin_amdgcn_rcpf(s);
  }
  u16x8 bp8[2][4];
#pragma unroll
  for (int s2 = 0; s2 < 2; ++s2)
#pragma unroll
    for (int nq = 0; nq < 4; ++nq)
      bp8[s2][nq] = pack8(st[2 * s2][nq], st[2 * s2 + 1][nq]);

  // ---- PV: out^T += V^T . P^T ----
  f32x4 ot[2][4];
#pragma unroll
  for (int md = 0; md < 2; ++md)
#pragma unroll
    for (int nq = 0; nq < 4; ++nq) ot[md][nq] = zero4;
#pragma unroll
  for (int s2 = 0; s2 < 2; ++s2)
#pragma unroll
    for (int md = 0; md < 2; ++md)
#pragma unroll
      for (int nq = 0; nq < 4; ++nq)
        ot[md][nq] = mfma32(va8[s2][md], bp8[s2][nq], ot[md][nq]);

  // ---- stage attn-out bf16 into ao, normalized per (head, query) HERE ----
#pragma unroll
  for (int md = 0; md < 2; ++md)
#pragma unroll
    for (int nq = 0; nq < 4; ++nq) {
      int tok = nq * 16 + q15;
      int cb = (h * 64 + md * 32 + g * 8) ^ rs;  // tok&7 == q15&7
      uint2 w2;
      w2.x = pk2n(ot[md][nq][0] * rc[nq], ot[md][nq][1] * rc[nq]);
      w2.y = pk2n(ot[md][nq][2] * rc[nq], ot[md][nq][3] * rc[nq]);
      *(uint2*)(ao + tok * 256 + cb) = w2;
    }
  __syncthreads();  // B1: attn-out complete

  // ---- proj weights/bias loaded here (short live range, L2-hot) ----
  u16x8 wp[4][2];
#pragma unroll
  for (int ks = 0; ks < 4; ++ks)
#pragma unroll
    for (int n = 0; n < 2; ++n)
      wp[ks][n] = *(const u16x8*)(wpb + (size_t)(h * 32 + n * 16 + q15) * 256 + ks * 64 + g * 16);
  f32x4 bv[2];
  bv[0] = *(const f32x4*)(bproj + h * 32 + g * 4);
  bv[1] = *(const f32x4*)(bproj + h * 32 + 16 + g * 4);

  // ---- proj GEMM (transposed): po = Wp^T . ao^T -> [ch][tok], f32x4 stores ----
  f32x4 po[2][4];
#pragma unroll
  for (int n = 0; n < 2; ++n)
#pragma unroll
    for (int t = 0; t < 4; ++t) po[n][t] = zero4;
#pragma unroll
  for (int ks = 0; ks < 4; ++ks) {
    u16x8 axb[4];
#pragma unroll
    for (int t = 0; t < 4; ++t)
      axb[t] = *(const u16x8*)(ao + (t * 16 + q15) * 256 + ((ks * 64 + g * 16) ^ rs));
#pragma unroll
    for (int n = 0; n < 2; ++n)
#pragma unroll
      for (int t = 0; t < 4; ++t)
        po[n][t] = mfma32(wp[ks][n], axb[t], po[n][t]);  // [ch][tok]
  }
  float* op = out + wbase;
#pragma unroll
  for (int n = 0; n < 2; ++n)
#pragma unroll
    for (int t = 0; t < 4; ++t) {
      f32x4 vs = po[n][t] + bv[n];
      *(f32x4*)(op + (size_t)(t * 16 + q15) * 128 + h * 32 + n * 16 + g * 4) = vs;
    }
}

extern "C" void kernel_launch(void* const* d_in, const int* in_sizes, int n_in,
                              void* d_out, int out_size, void* d_ws, size_t ws_size,
                              hipStream_t stream) {
  const float* x     = (const float*)d_in[0];
  const float* wqkv  = (const float*)d_in[1];
  const float* wproj = (const float*)d_in[2];
  const float* bproj = (const float*)d_in[3];
  const float* btab  = (const float*)d_in[4];
  char* ws = (char*)d_ws;
  unsigned short* wqkvt  = (unsigned short*)ws;             // 98304 B
  unsigned short* wprojt = (unsigned short*)(ws + 98304);   // 32768 B
  float* biasf           = (float*)(ws + 131072);           // 65536 B

  prep_kernel<<<320, 256, 0, stream>>>(wqkv, wproj, btab, wqkvt, wprojt, biasf);
  attn_kernel<<<4096, 256, 0, stream>>>(x, wqkvt, wprojt, biasf, bproj, (float*)d_out);
}

// Round 15
// 115.198 us; speedup vs baseline: 2.0049x; 1.1865x over previous
//
#include <hip/hip_runtime.h>
#include <cstdint>
#include <cstddef>

// Fused Swin-style window attention for MI355X (gfx950), round 15.
// Occupancy curve is now 4 points: 21/30/41% -> 110.8/136.7/241us. Extra waves
// are always bought with register starvation and always lose. R15 = R13's
// instruction-lean kernel (mfma32 concat attention, f32 bias into accumulators,
// post-barrier wp/bv, correct per-head normalization) with the ONE change:
// launch_bounds(256,2) -- the register-comfortable cap of every fast run.

typedef float f32x4 __attribute__((ext_vector_type(4)));
typedef __bf16 bf16x8 __attribute__((ext_vector_type(8)));
typedef unsigned short u16x8 __attribute__((ext_vector_type(8)));

__device__ __forceinline__ unsigned short bfs(float f) {
  return __builtin_bit_cast(unsigned short, (__bf16)f);  // HW RNE cvt
}
__device__ __forceinline__ unsigned pk2n(float a, float b) {
  return (unsigned)bfs(a) | ((unsigned)bfs(b) << 16);
}
__device__ __forceinline__ u16x8 pack8(f32x4 a, f32x4 b) {
  u16x8 r;
  r[0] = bfs(a[0]); r[1] = bfs(a[1]); r[2] = bfs(a[2]); r[3] = bfs(a[3]);
  r[4] = bfs(b[0]); r[5] = bfs(b[1]); r[6] = bfs(b[2]); r[7] = bfs(b[3]);
  return r;
}
__device__ __forceinline__ f32x4 mfma32(u16x8 a, u16x8 b, f32x4 c) {
  return __builtin_amdgcn_mfma_f32_16x16x32_bf16(
      __builtin_bit_cast(bf16x8, a), __builtin_bit_cast(bf16x8, b), c, 0, 0, 0);
}

// ---------------- prep: weights^T -> bf16, rel-pos bias -> f32 frag layout ----------
// ws: [0,98304)        wqkv_t bf16 [384 cols][128 k]   (Q cols scaled by log2e/sqrt(hd))
//     [98304,131072)   wproj_t bf16 [128 cols][128 k]
//     [131072,196608)  bias f32 [h][mk][nq][lane][i]   (S^T frag layout, * log2e)
__global__ void prep_kernel(const float* __restrict__ wqkv, const float* __restrict__ wproj,
                            const float* __restrict__ btab,
                            unsigned short* __restrict__ wqkvt,
                            unsigned short* __restrict__ wprojt,
                            float* __restrict__ biasf) {
  int t = blockIdx.x * 256 + threadIdx.x;
  if (t < 49152) {
    int c = t >> 7, k = t & 127;
    float v = wqkv[k * 384 + c];
    if (c < 128) v *= 0.25503486f;  // log2(e)/sqrt(32)
    wqkvt[t] = bfs(v);
  } else if (t < 65536) {
    int t2 = t - 49152;
    int c = t2 >> 7, k = t2 & 127;
    wprojt[t2] = bfs(wproj[k * 128 + c]);
  } else if (t < 81920) {
    int t3 = t - 65536;
    int i = t3 & 3, lane = (t3 >> 2) & 63, nq = (t3 >> 8) & 3, mk = (t3 >> 10) & 3, h = t3 >> 12;
    int key = mk * 16 + ((lane >> 4) << 2) + i;  // S^T row (C-layout)
    int q   = nq * 16 + (lane & 15);             // S^T col
    int idx = ((q >> 3) - (key >> 3) + 7) * 15 + ((q & 7) - (key & 7) + 7);
    biasf[t3] = btab[idx * 4 + h] * 1.4426950408889634f;
  }
}

// ---------------- fused attention: 1 window / block ----------------
__global__ __launch_bounds__(256, 2) void attn_kernel(
    const float* __restrict__ x, const unsigned short* __restrict__ wqkvt,
    const unsigned short* __restrict__ wprojt, const float* __restrict__ biasf,
    const float* __restrict__ bproj, float* __restrict__ out) {
  __shared__ char lds[32768];
  char* xs = lds;           // bf16 x tile [64 tok][128 c], byte-XOR swizzled
  char* ao = lds + 16384;   // bf16 attn-out tile, same swizzle
  const int tid = threadIdx.x;
  const int lane = tid & 63;
  const int h = tid >> 6;   // wave = head
  const int g = lane >> 4;
  const int q15 = lane & 15;
  const int rs = (q15 & 7) << 4;  // read swizzle; row%8 == q15%8 for our reads
  const size_t wbase = (size_t)blockIdx.x * 8192;
  const f32x4 zero4 = {0.f, 0.f, 0.f, 0.f};
  const char* wqb = (const char*)wqkvt;
  const char* wpb = (const char*)wprojt;

  // ---- stage x: f32 -> bf16 (native cvt_pk), swizzled ----
  {
    const int row = tid >> 2;
    const int cb = (tid & 3) * 32;
    const float* xp = x + wbase + row * 128 + cb;
#pragma unroll
    for (int u = 0; u < 4; ++u) {
      f32x4 a = *(const f32x4*)(xp + u * 8);
      f32x4 b = *(const f32x4*)(xp + u * 8 + 4);
      uint4 p;
      p.x = pk2n(a[0], a[1]); p.y = pk2n(a[2], a[3]);
      p.z = pk2n(b[0], b[1]); p.w = pk2n(b[2], b[3]);
      int byte = row * 256 + (((cb * 2) + u * 16) ^ ((row & 7) << 4));
      *(uint4*)(xs + byte) = p;
    }
  }
  __syncthreads();  // A: x tile visible

  // ---- sub-pass A: Q^T, K^T = Wqk^T . x^T ----
  f32x4 qt[2][4], kt[2][4];
#pragma unroll
  for (int m = 0; m < 2; ++m)
#pragma unroll
    for (int t = 0; t < 4; ++t) { qt[m][t] = zero4; kt[m][t] = zero4; }
#pragma unroll
  for (int ks = 0; ks < 4; ++ks) {
    u16x8 xb[4];
#pragma unroll
    for (int t = 0; t < 4; ++t)
      xb[t] = *(const u16x8*)(xs + (t * 16 + q15) * 256 + ((ks * 64 + g * 16) ^ rs));
    const int kb = ks * 64 + g * 16;
    u16x8 wq[2], wk[2];
#pragma unroll
    for (int m = 0; m < 2; ++m) {
      int col = h * 32 + m * 16 + q15;
      wq[m] = *(const u16x8*)(wqb + (size_t)col * 256 + kb);
      wk[m] = *(const u16x8*)(wqb + (size_t)(col + 128) * 256 + kb);
    }
#pragma unroll
    for (int m = 0; m < 2; ++m)
#pragma unroll
      for (int t = 0; t < 4; ++t) {
        qt[m][t] = mfma32(wq[m], xb[t], qt[m][t]);  // [c][tok]
        kt[m][t] = mfma32(wk[m], xb[t], kt[m][t]);
      }
  }
  u16x8 qp8[4], kp8[4];
#pragma unroll
  for (int t = 0; t < 4; ++t) {
    qp8[t] = pack8(qt[0][t], qt[1][t]);  // k=32 concat frags (validated R8)
    kp8[t] = pack8(kt[0][t], kt[1][t]);
  }

  // ---- sub-pass B: V = x . Wv (re-read xs; QK accs freed) ----
  f32x4 vv[4][2];
#pragma unroll
  for (int t = 0; t < 4; ++t) { vv[t][0] = zero4; vv[t][1] = zero4; }
#pragma unroll
  for (int ks = 0; ks < 4; ++ks) {
    u16x8 xb[4];
#pragma unroll
    for (int t = 0; t < 4; ++t)
      xb[t] = *(const u16x8*)(xs + (t * 16 + q15) * 256 + ((ks * 64 + g * 16) ^ rs));
    const int kb = ks * 64 + g * 16;
    u16x8 wv[2];
#pragma unroll
    for (int n = 0; n < 2; ++n)
      wv[n] = *(const u16x8*)(wqb + (size_t)(h * 32 + n * 16 + q15 + 256) * 256 + kb);
#pragma unroll
    for (int t = 0; t < 4; ++t)
#pragma unroll
      for (int n = 0; n < 2; ++n)
        vv[t][n] = mfma32(xb[t], wv[n], vv[t][n]);  // [tok][d]
  }
  u16x8 va8[2][2];
#pragma unroll
  for (int s2 = 0; s2 < 2; ++s2)
#pragma unroll
    for (int n = 0; n < 2; ++n)
      va8[s2][n] = pack8(vv[2 * s2][n], vv[2 * s2 + 1][n]);

  // ---- S^T = K.Q^T + bias (f32 bias loaded straight into accumulators, L2-hot) ----
  f32x4 st[4][4];
  const f32x4* bst = (const f32x4*)biasf;
#pragma unroll
  for (int mk = 0; mk < 4; ++mk)
#pragma unroll
    for (int nq = 0; nq < 4; ++nq)
      st[mk][nq] = bst[((h * 4 + mk) * 4 + nq) * 64 + lane];
#pragma unroll
  for (int mk = 0; mk < 4; ++mk)
#pragma unroll
    for (int nq = 0; nq < 4; ++nq)
      st[mk][nq] = mfma32(kp8[mk], qp8[nq], st[mk][nq]);

  // ---- softmax (logits pre-scaled by log2e; no max-subtract needed) ----
  float rc[4];
#pragma unroll
  for (int nq = 0; nq < 4; ++nq) {
    float s = 0.f;
#pragma unroll
    for (int mk = 0; mk < 4; ++mk)
#pragma unroll
      for (int i = 0; i < 4; ++i) {
        float e = exp2f(st[mk][nq][i]);
        st[mk][nq][i] = e;
        s += e;
      }
    s += __shfl_xor(s, 16);
    s += __shfl_xor(s, 32);
    rc[nq] = __builtin_amdgcn_rcpf(s);
  }
  u16x8 bp8[2][4];
#pragma unroll
  for (int s2 = 0; s2 < 2; ++s2)
#pragma unroll
    for (int nq = 0; nq < 4; ++nq)
      bp8[s2][nq] = pack8(st[2 * s2][nq], st[2 * s2 + 1][nq]);

  // ---- PV: out^T += V^T . P^T ----
  f32x4 ot[2][4];
#pragma unroll
  for (int md = 0; md < 2; ++md)
#pragma unroll
    for (int nq = 0; nq < 4; ++nq) ot[md][nq] = zero4;
#pragma unroll
  for (int s2 = 0; s2 < 2; ++s2)
#pragma unroll
    for (int md = 0; md < 2; ++md)
#pragma unroll
      for (int nq = 0; nq < 4; ++nq)
        ot[md][nq] = mfma32(va8[s2][md], bp8[s2][nq], ot[md][nq]);

  // ---- stage attn-out bf16 into ao, normalized per (head, query) ----
#pragma unroll
  for (int md = 0; md < 2; ++md)
#pragma unroll
    for (int nq = 0; nq < 4; ++nq) {
      int tok = nq * 16 + q15;
      int cb = (h * 64 + md * 32 + g * 8) ^ rs;  // tok&7 == q15&7
      uint2 w2;
      w2.x = pk2n(ot[md][nq][0] * rc[nq], ot[md][nq][1] * rc[nq]);
      w2.y = pk2n(ot[md][nq][2] * rc[nq], ot[md][nq][3] * rc[nq]);
      *(uint2*)(ao + tok * 256 + cb) = w2;
    }
  __syncthreads();  // B1: attn-out complete

  // ---- proj weights/bias loaded here (short live range, L2-hot) ----
  u16x8 wp[4][2];
#pragma unroll
  for (int ks = 0; ks < 4; ++ks)
#pragma unroll
    for (int n = 0; n < 2; ++n)
      wp[ks][n] = *(const u16x8*)(wpb + (size_t)(h * 32 + n * 16 + q15) * 256 + ks * 64 + g * 16);
  f32x4 bv[2];
  bv[0] = *(const f32x4*)(bproj + h * 32 + g * 4);
  bv[1] = *(const f32x4*)(bproj + h * 32 + 16 + g * 4);

  // ---- proj GEMM (transposed): po = Wp^T . ao^T -> [ch][tok], f32x4 stores ----
  f32x4 po[2][4];
#pragma unroll
  for (int n = 0; n < 2; ++n)
#pragma unroll
    for (int t = 0; t < 4; ++t) po[n][t] = zero4;
#pragma unroll
  for (int ks = 0; ks < 4; ++ks) {
    u16x8 axb[4];
#pragma unroll
    for (int t = 0; t < 4; ++t)
      axb[t] = *(const u16x8*)(ao + (t * 16 + q15) * 256 + ((ks * 64 + g * 16) ^ rs));
#pragma unroll
    for (int n = 0; n < 2; ++n)
#pragma unroll
      for (int t = 0; t < 4; ++t)
        po[n][t] = mfma32(wp[ks][n], axb[t], po[n][t]);  // [ch][tok]
  }
  float* op = out + wbase;
#pragma unroll
  for (int n = 0; n < 2; ++n)
#pragma unroll
    for (int t = 0; t < 4; ++t) {
      f32x4 vs = po[n][t] + bv[n];
      *(f32x4*)(op + (size_t)(t * 16 + q15) * 128 + h * 32 + n * 16 + g * 4) = vs;
    }
}

extern "C" void kernel_launch(void* const* d_in, const int* in_sizes, int n_in,
                              void* d_out, int out_size, void* d_ws, size_t ws_size,
                              hipStream_t stream) {
  const float* x     = (const float*)d_in[0];
  const float* wqkv  = (const float*)d_in[1];
  const float* wproj = (const float*)d_in[2];
  const float* bproj = (const float*)d_in[3];
  const float* btab  = (const float*)d_in[4];
  char* ws = (char*)d_ws;
  unsigned short* wqkvt  = (unsigned short*)ws;             // 98304 B
  unsigned short* wprojt = (unsigned short*)(ws + 98304);   // 32768 B
  float* biasf           = (float*)(ws + 131072);           // 65536 B

  prep_kernel<<<320, 256, 0, stream>>>(wqkv, wproj, btab, wqkvt, wprojt, biasf);
  attn_kernel<<<4096, 256, 0, stream>>>(x, wqkvt, wprojt, biasf, bproj, (float*)d_out);
}

// Round 16
// 110.414 us; speedup vs baseline: 2.0918x; 1.0433x over previous
//
#include <hip/hip_runtime.h>
#include <cstdint>
#include <cstddef>

// Fused Swin-style window attention for MI355X (gfx950), round 16.
// R15 lesson: at (256,2) registers are abundant; deferring L2 loads (bias at
// S^T-time, wp/bv post-barrier) put their latency ON the critical path and
// cost 4% vs R6. R16 = R6's latency-optimal load placement (bias bf16 held
// from block start; wp/bv issued pre-barrier) + the validated mfma32-concat
// attention (32 matrix ops vs 64) + correct per-head normalization.

typedef float f32x4 __attribute__((ext_vector_type(4)));
typedef __bf16 bf16x8 __attribute__((ext_vector_type(8)));
typedef unsigned short u16x8 __attribute__((ext_vector_type(8)));
typedef unsigned short u16x4 __attribute__((ext_vector_type(4)));

__device__ __forceinline__ unsigned short bfs(float f) {
  return __builtin_bit_cast(unsigned short, (__bf16)f);  // HW RNE cvt
}
__device__ __forceinline__ unsigned pk2n(float a, float b) {
  return (unsigned)bfs(a) | ((unsigned)bfs(b) << 16);
}
__device__ __forceinline__ u16x8 pack8(f32x4 a, f32x4 b) {
  u16x8 r;
  r[0] = bfs(a[0]); r[1] = bfs(a[1]); r[2] = bfs(a[2]); r[3] = bfs(a[3]);
  r[4] = bfs(b[0]); r[5] = bfs(b[1]); r[6] = bfs(b[2]); r[7] = bfs(b[3]);
  return r;
}
__device__ __forceinline__ f32x4 bf4up(u16x4 v) {
  f32x4 r;
  r[0] = __builtin_bit_cast(float, (unsigned)v[0] << 16);
  r[1] = __builtin_bit_cast(float, (unsigned)v[1] << 16);
  r[2] = __builtin_bit_cast(float, (unsigned)v[2] << 16);
  r[3] = __builtin_bit_cast(float, (unsigned)v[3] << 16);
  return r;
}
__device__ __forceinline__ f32x4 mfma32(u16x8 a, u16x8 b, f32x4 c) {
  return __builtin_amdgcn_mfma_f32_16x16x32_bf16(
      __builtin_bit_cast(bf16x8, a), __builtin_bit_cast(bf16x8, b), c, 0, 0, 0);
}

// ---------------- prep: weights^T -> bf16, rel-pos bias -> bf16 frag layout ----------
// ws: [0,98304)        wqkv_t bf16 [384 cols][128 k]   (Q cols scaled by log2e/sqrt(hd))
//     [98304,131072)   wproj_t bf16 [128 cols][128 k]
//     [131072,163840)  bias bf16 [h][mk][nq][lane][i]  (S^T frag layout, * log2e)
__global__ void prep_kernel(const float* __restrict__ wqkv, const float* __restrict__ wproj,
                            const float* __restrict__ btab,
                            unsigned short* __restrict__ wqkvt,
                            unsigned short* __restrict__ wprojt,
                            unsigned short* __restrict__ biasbf) {
  int t = blockIdx.x * 256 + threadIdx.x;
  if (t < 49152) {
    int c = t >> 7, k = t & 127;
    float v = wqkv[k * 384 + c];
    if (c < 128) v *= 0.25503486f;  // log2(e)/sqrt(32)
    wqkvt[t] = bfs(v);
  } else if (t < 65536) {
    int t2 = t - 49152;
    int c = t2 >> 7, k = t2 & 127;
    wprojt[t2] = bfs(wproj[k * 128 + c]);
  } else if (t < 81920) {
    int t3 = t - 65536;
    int i = t3 & 3, lane = (t3 >> 2) & 63, nq = (t3 >> 8) & 3, mk = (t3 >> 10) & 3, h = t3 >> 12;
    int key = mk * 16 + ((lane >> 4) << 2) + i;  // S^T row (C-layout)
    int q   = nq * 16 + (lane & 15);             // S^T col
    int idx = ((q >> 3) - (key >> 3) + 7) * 15 + ((q & 7) - (key & 7) + 7);
    biasbf[t3] = bfs(btab[idx * 4 + h] * 1.4426950408889634f);
  }
}

// ---------------- fused attention: 1 window / block ----------------
__global__ __launch_bounds__(256, 2) void attn_kernel(
    const float* __restrict__ x, const unsigned short* __restrict__ wqkvt,
    const unsigned short* __restrict__ wprojt, const unsigned short* __restrict__ biasbf,
    const float* __restrict__ bproj, float* __restrict__ out) {
  __shared__ char lds[32768];
  char* xs = lds;           // bf16 x tile [64 tok][128 c], byte-XOR swizzled
  char* ao = lds + 16384;   // bf16 attn-out tile, same swizzle
  const int tid = threadIdx.x;
  const int lane = tid & 63;
  const int h = tid >> 6;   // wave = head
  const int g = lane >> 4;
  const int q15 = lane & 15;
  const int rs = (q15 & 7) << 4;  // read swizzle; row%8 == q15%8 for our reads
  const size_t wbase = (size_t)blockIdx.x * 8192;
  const f32x4 zero4 = {0.f, 0.f, 0.f, 0.f};
  const char* wqb = (const char*)wqkvt;
  const char* wpb = (const char*)wprojt;

  // ---- early loads: bias bf16 frags (L2-hot; latency hides under x HBM wait) ----
  u16x4 bias[4][4];
#pragma unroll
  for (int mk = 0; mk < 4; ++mk)
#pragma unroll
    for (int nq = 0; nq < 4; ++nq)
      bias[mk][nq] = ((const u16x4*)biasbf)[((h * 4 + mk) * 4 + nq) * 64 + lane];

  // ---- stage x: f32 -> bf16 (native cvt_pk), swizzled ----
  {
    const int row = tid >> 2;
    const int cb = (tid & 3) * 32;
    const float* xp = x + wbase + row * 128 + cb;
#pragma unroll
    for (int u = 0; u < 4; ++u) {
      f32x4 a = *(const f32x4*)(xp + u * 8);
      f32x4 b = *(const f32x4*)(xp + u * 8 + 4);
      uint4 p;
      p.x = pk2n(a[0], a[1]); p.y = pk2n(a[2], a[3]);
      p.z = pk2n(b[0], b[1]); p.w = pk2n(b[2], b[3]);
      int byte = row * 256 + (((cb * 2) + u * 16) ^ ((row & 7) << 4));
      *(uint4*)(xs + byte) = p;
    }
  }
  __syncthreads();  // A: x tile visible

  // ---- sub-pass A: Q^T, K^T = Wqk^T . x^T ----
  f32x4 qt[2][4], kt[2][4];
#pragma unroll
  for (int m = 0; m < 2; ++m)
#pragma unroll
    for (int t = 0; t < 4; ++t) { qt[m][t] = zero4; kt[m][t] = zero4; }
#pragma unroll
  for (int ks = 0; ks < 4; ++ks) {
    u16x8 xb[4];
#pragma unroll
    for (int t = 0; t < 4; ++t)
      xb[t] = *(const u16x8*)(xs + (t * 16 + q15) * 256 + ((ks * 64 + g * 16) ^ rs));
    const int kb = ks * 64 + g * 16;
    u16x8 wq[2], wk[2];
#pragma unroll
    for (int m = 0; m < 2; ++m) {
      int col = h * 32 + m * 16 + q15;
      wq[m] = *(const u16x8*)(wqb + (size_t)col * 256 + kb);
      wk[m] = *(const u16x8*)(wqb + (size_t)(col + 128) * 256 + kb);
    }
#pragma unroll
    for (int m = 0; m < 2; ++m)
#pragma unroll
      for (int t = 0; t < 4; ++t) {
        qt[m][t] = mfma32(wq[m], xb[t], qt[m][t]);  // [c][tok]
        kt[m][t] = mfma32(wk[m], xb[t], kt[m][t]);
      }
  }
  u16x8 qp8[4], kp8[4];
#pragma unroll
  for (int t = 0; t < 4; ++t) {
    qp8[t] = pack8(qt[0][t], qt[1][t]);  // k=32 concat frags (validated R8)
    kp8[t] = pack8(kt[0][t], kt[1][t]);
  }

  // ---- sub-pass B: V = x . Wv (re-read xs; QK accs freed) ----
  f32x4 vv[4][2];
#pragma unroll
  for (int t = 0; t < 4; ++t) { vv[t][0] = zero4; vv[t][1] = zero4; }
#pragma unroll
  for (int ks = 0; ks < 4; ++ks) {
    u16x8 xb[4];
#pragma unroll
    for (int t = 0; t < 4; ++t)
      xb[t] = *(const u16x8*)(xs + (t * 16 + q15) * 256 + ((ks * 64 + g * 16) ^ rs));
    const int kb = ks * 64 + g * 16;
    u16x8 wv[2];
#pragma unroll
    for (int n = 0; n < 2; ++n)
      wv[n] = *(const u16x8*)(wqb + (size_t)(h * 32 + n * 16 + q15 + 256) * 256 + kb);
#pragma unroll
    for (int t = 0; t < 4; ++t)
#pragma unroll
      for (int n = 0; n < 2; ++n)
        vv[t][n] = mfma32(xb[t], wv[n], vv[t][n]);  // [tok][d]
  }
  u16x8 va8[2][2];
#pragma unroll
  for (int s2 = 0; s2 < 2; ++s2)
#pragma unroll
    for (int n = 0; n < 2; ++n)
      va8[s2][n] = pack8(vv[2 * s2][n], vv[2 * s2 + 1][n]);

  // ---- S^T = K.Q^T + bias (bias from regs, loaded at block start) ----
  f32x4 st[4][4];
#pragma unroll
  for (int mk = 0; mk < 4; ++mk)
#pragma unroll
    for (int nq = 0; nq < 4; ++nq)
      st[mk][nq] = bf4up(bias[mk][nq]);
#pragma unroll
  for (int mk = 0; mk < 4; ++mk)
#pragma unroll
    for (int nq = 0; nq < 4; ++nq)
      st[mk][nq] = mfma32(kp8[mk], qp8[nq], st[mk][nq]);

  // ---- softmax (logits pre-scaled by log2e; no max-subtract needed) ----
  float rc[4];
#pragma unroll
  for (int nq = 0; nq < 4; ++nq) {
    float s = 0.f;
#pragma unroll
    for (int mk = 0; mk < 4; ++mk)
#pragma unroll
      for (int i = 0; i < 4; ++i) {
        float e = exp2f(st[mk][nq][i]);
        st[mk][nq][i] = e;
        s += e;
      }
    s += __shfl_xor(s, 16);
    s += __shfl_xor(s, 32);
    rc[nq] = __builtin_amdgcn_rcpf(s);
  }
  u16x8 bp8[2][4];
#pragma unroll
  for (int s2 = 0; s2 < 2; ++s2)
#pragma unroll
    for (int nq = 0; nq < 4; ++nq)
      bp8[s2][nq] = pack8(st[2 * s2][nq], st[2 * s2 + 1][nq]);

  // ---- PV: out^T += V^T . P^T ----
  f32x4 ot[2][4];
#pragma unroll
  for (int md = 0; md < 2; ++md)
#pragma unroll
    for (int nq = 0; nq < 4; ++nq) ot[md][nq] = zero4;
#pragma unroll
  for (int s2 = 0; s2 < 2; ++s2)
#pragma unroll
    for (int md = 0; md < 2; ++md)
#pragma unroll
      for (int nq = 0; nq < 4; ++nq)
        ot[md][nq] = mfma32(va8[s2][md], bp8[s2][nq], ot[md][nq]);

  // ---- stage attn-out bf16 into ao, normalized per (head, query) ----
#pragma unroll
  for (int md = 0; md < 2; ++md)
#pragma unroll
    for (int nq = 0; nq < 4; ++nq) {
      int tok = nq * 16 + q15;
      int cb = (h * 64 + md * 32 + g * 8) ^ rs;  // tok&7 == q15&7
      uint2 w2;
      w2.x = pk2n(ot[md][nq][0] * rc[nq], ot[md][nq][1] * rc[nq]);
      w2.y = pk2n(ot[md][nq][2] * rc[nq], ot[md][nq][3] * rc[nq]);
      *(uint2*)(ao + tok * 256 + cb) = w2;
    }

  // ---- prefetch proj weights/bias BEFORE the barrier (latency hides in wait) ----
  u16x8 wp[4][2];
#pragma unroll
  for (int ks = 0; ks < 4; ++ks)
#pragma unroll
    for (int n = 0; n < 2; ++n)
      wp[ks][n] = *(const u16x8*)(wpb + (size_t)(h * 32 + n * 16 + q15) * 256 + ks * 64 + g * 16);
  f32x4 bv[2];
  bv[0] = *(const f32x4*)(bproj + h * 32 + g * 4);
  bv[1] = *(const f32x4*)(bproj + h * 32 + 16 + g * 4);
  __syncthreads();  // B1: attn-out complete

  // ---- proj GEMM (transposed): po = Wp^T . ao^T -> [ch][tok], f32x4 stores ----
  f32x4 po[2][4];
#pragma unroll
  for (int n = 0; n < 2; ++n)
#pragma unroll
    for (int t = 0; t < 4; ++t) po[n][t] = zero4;
#pragma unroll
  for (int ks = 0; ks < 4; ++ks) {
    u16x8 axb[4];
#pragma unroll
    for (int t = 0; t < 4; ++t)
      axb[t] = *(const u16x8*)(ao + (t * 16 + q15) * 256 + ((ks * 64 + g * 16) ^ rs));
#pragma unroll
    for (int n = 0; n < 2; ++n)
#pragma unroll
      for (int t = 0; t < 4; ++t)
        po[n][t] = mfma32(wp[ks][n], axb[t], po[n][t]);  // [ch][tok]
  }
  float* op = out + wbase;
#pragma unroll
  for (int n = 0; n < 2; ++n)
#pragma unroll
    for (int t = 0; t < 4; ++t) {
      f32x4 vs = po[n][t] + bv[n];
      *(f32x4*)(op + (size_t)(t * 16 + q15) * 128 + h * 32 + n * 16 + g * 4) = vs;
    }
}

extern "C" void kernel_launch(void* const* d_in, const int* in_sizes, int n_in,
                              void* d_out, int out_size, void* d_ws, size_t ws_size,
                              hipStream_t stream) {
  const float* x     = (const float*)d_in[0];
  const float* wqkv  = (const float*)d_in[1];
  const float* wproj = (const float*)d_in[2];
  const float* bproj = (const float*)d_in[3];
  const float* btab  = (const float*)d_in[4];
  char* ws = (char*)d_ws;
  unsigned short* wqkvt  = (unsigned short*)ws;             // 98304 B
  unsigned short* wprojt = (unsigned short*)(ws + 98304);   // 32768 B
  unsigned short* biasbf = (unsigned short*)(ws + 131072);  // 32768 B

  prep_kernel<<<320, 256, 0, stream>>>(wqkv, wproj, btab, wqkvt, wprojt, biasbf);
  attn_kernel<<<4096, 256, 0, stream>>>(x, wqkvt, wprojt, biasbf, bproj, (float*)d_out);
}

// Round 17
// 103.087 us; speedup vs baseline: 2.2404x; 1.0711x over previous
//
#include <hip/hip_runtime.h>
#include <cstdint>
#include <cstddef>

// Fused Swin-style window attention for MI355X (gfx950), round 17.
// Plateau diagnosis (R6..R16, 110-115us): 4-wave blocks are latency-bound at
// 8 waves/CU; register caps spill because 4 waves must hold ~45 acc regs/lane.
// R17: 8-wave blocks (512 thr), Q/K/V passed through LDS (64KB) instead of
// registers. Per-wave MFMA halves (136->80), peak live regs ~110 -> a 128-reg
// cap is SAFE -> launch_bounds(512,4) = 16 waves/CU, 2x latency hiding.
//  - Q,K stored [tok][ch] bf16; V stored [d][tok] with key-permuted columns
//    matching bp8's concat k-slot order (derived, see Vt write addr).
//  - All LDS tiles share one XOR swizzle; every row index == lane&15 (mod 8).
//  - attention wave = (head, query-half); qkv/proj wave = 16-ch block.
//  - 3 barriers; ao tile aliases the dead x tile.

typedef float f32x4 __attribute__((ext_vector_type(4)));
typedef __bf16 bf16x8 __attribute__((ext_vector_type(8)));
typedef unsigned short u16x8 __attribute__((ext_vector_type(8)));
typedef unsigned short u16x4 __attribute__((ext_vector_type(4)));

__device__ __forceinline__ unsigned short bfs(float f) {
  return __builtin_bit_cast(unsigned short, (__bf16)f);  // HW RNE cvt
}
__device__ __forceinline__ unsigned pk2n(float a, float b) {
  return (unsigned)bfs(a) | ((unsigned)bfs(b) << 16);
}
__device__ __forceinline__ uint2 pku2(f32x4 v) {
  uint2 r; r.x = pk2n(v[0], v[1]); r.y = pk2n(v[2], v[3]); return r;
}
__device__ __forceinline__ u16x8 pack8(f32x4 a, f32x4 b) {
  u16x8 r;
  r[0] = bfs(a[0]); r[1] = bfs(a[1]); r[2] = bfs(a[2]); r[3] = bfs(a[3]);
  r[4] = bfs(b[0]); r[5] = bfs(b[1]); r[6] = bfs(b[2]); r[7] = bfs(b[3]);
  return r;
}
__device__ __forceinline__ f32x4 bf4up(u16x4 v) {
  f32x4 r;
  r[0] = __builtin_bit_cast(float, (unsigned)v[0] << 16);
  r[1] = __builtin_bit_cast(float, (unsigned)v[1] << 16);
  r[2] = __builtin_bit_cast(float, (unsigned)v[2] << 16);
  r[3] = __builtin_bit_cast(float, (unsigned)v[3] << 16);
  return r;
}
__device__ __forceinline__ f32x4 mfma32(u16x8 a, u16x8 b, f32x4 c) {
  return __builtin_amdgcn_mfma_f32_16x16x32_bf16(
      __builtin_bit_cast(bf16x8, a), __builtin_bit_cast(bf16x8, b), c, 0, 0, 0);
}

// ---------------- prep: weights^T -> bf16, rel-pos bias -> bf16 frag layout ----------
// ws: [0,98304)        wqkv_t bf16 [384 cols][128 k]   (Q cols scaled by log2e/sqrt(hd))
//     [98304,131072)   wproj_t bf16 [128 cols][128 k]
//     [131072,163840)  bias bf16 [h][qh][mk][nq][lane][i]  (S^T frag layout, * log2e)
__global__ void prep_kernel(const float* __restrict__ wqkv, const float* __restrict__ wproj,
                            const float* __restrict__ btab,
                            unsigned short* __restrict__ wqkvt,
                            unsigned short* __restrict__ wprojt,
                            unsigned short* __restrict__ biasbf) {
  int t = blockIdx.x * 256 + threadIdx.x;
  if (t < 49152) {
    int c = t >> 7, k = t & 127;
    float v = wqkv[k * 384 + c];
    if (c < 128) v *= 0.25503486f;  // log2(e)/sqrt(32)
    wqkvt[t] = bfs(v);
  } else if (t < 65536) {
    int t2 = t - 49152;
    int c = t2 >> 7, k = t2 & 127;
    wprojt[t2] = bfs(wproj[k * 128 + c]);
  } else if (t < 81920) {
    int t3 = t - 65536;
    int i = t3 & 3, lane = (t3 >> 2) & 63;
    int nq = (t3 >> 8) & 1, mk = (t3 >> 9) & 3, qh = (t3 >> 11) & 1, h = (t3 >> 12) & 3;
    int key = mk * 16 + ((lane >> 4) << 2) + i;      // S^T row (C-layout)
    int q   = qh * 32 + nq * 16 + (lane & 15);       // S^T col
    int idx = ((q >> 3) - (key >> 3) + 7) * 15 + ((q & 7) - (key & 7) + 7);
    biasbf[t3] = bfs(btab[idx * 4 + h] * 1.4426950408889634f);
  }
}

// ---------------- fused attention: 1 window / block, 8 waves ----------------
__global__ __launch_bounds__(512, 4) void attn_kernel(
    const float* __restrict__ x, const unsigned short* __restrict__ wqkvt,
    const unsigned short* __restrict__ wprojt, const unsigned short* __restrict__ biasbf,
    const float* __restrict__ bproj, float* __restrict__ out) {
  __shared__ char lds[65536];
  char* xs = lds;            // bf16 x tile [64 tok][128 ch]; reused as ao after B2
  char* Qs = lds + 16384;    // bf16 Q [64 tok][128 ch]
  char* Ks = lds + 32768;    // bf16 K [64 tok][128 ch]
  char* Vt = lds + 49152;    // bf16 V^T [128 d][64 key], key-permuted columns
  const int tid = threadIdx.x;
  const int w = tid >> 6;       // wave 0..7
  const int lane = tid & 63;
  const int g = lane >> 4;
  const int q15 = lane & 15;
  const int rs = (q15 & 7) << 4;  // XOR swizzle; all row indices == q15 (mod 8)
  const int h = w >> 1;           // attention: head
  const int qh = w & 1;           // attention: query half (32 queries)
  const size_t wbase = (size_t)blockIdx.x * 8192;
  const f32x4 zero4 = {0.f, 0.f, 0.f, 0.f};
  const char* wqb = (const char*)wqkvt;
  const char* wpb = (const char*)wprojt;

  // ---- early loads: bias frags (L2-hot; latency hides under x HBM wait) ----
  u16x4 bias[4][2];
#pragma unroll
  for (int mk = 0; mk < 4; ++mk)
#pragma unroll
    for (int nq = 0; nq < 2; ++nq)
      bias[mk][nq] = ((const u16x4*)biasbf)[(((h * 2 + qh) * 4 + mk) * 2 + nq) * 64 + lane];

  // ---- stage x: f32 -> bf16, swizzled [64 tok][128 ch] (512 thr: 16 f32 each) ----
  {
    const int row = tid >> 3;
    const int c8 = (tid & 7);  // 16-float column block
    const float* xp = x + wbase + row * 128 + c8 * 16;
    f32x4 a0 = *(const f32x4*)(xp + 0), a1 = *(const f32x4*)(xp + 4);
    f32x4 a2 = *(const f32x4*)(xp + 8), a3 = *(const f32x4*)(xp + 12);
    uint4 p0, p1;
    p0.x = pk2n(a0[0], a0[1]); p0.y = pk2n(a0[2], a0[3]);
    p0.z = pk2n(a1[0], a1[1]); p0.w = pk2n(a1[2], a1[3]);
    p1.x = pk2n(a2[0], a2[1]); p1.y = pk2n(a2[2], a2[3]);
    p1.z = pk2n(a3[0], a3[1]); p1.w = pk2n(a3[2], a3[3]);
    int swz = (row & 7) << 4;
    *(uint4*)(xs + row * 256 + ((c8 * 32 + 0)  ^ swz)) = p0;
    *(uint4*)(xs + row * 256 + ((c8 * 32 + 16) ^ swz)) = p1;
  }
  __syncthreads();  // B1: x tile visible

  // ---- qkv: wave w owns ch/d block w*16..w*16+15 for Q, K, V ----
  {
    f32x4 qa[4], ka[4], va[4];
#pragma unroll
    for (int t = 0; t < 4; ++t) { qa[t] = zero4; ka[t] = zero4; va[t] = zero4; }
#pragma unroll
    for (int ks = 0; ks < 4; ++ks) {
      u16x8 xb[4];
#pragma unroll
      for (int t = 0; t < 4; ++t)
        xb[t] = *(const u16x8*)(xs + (t * 16 + q15) * 256 + ((ks * 64 + g * 16) ^ rs));
      const int kb = ks * 64 + g * 16;
      u16x8 wqf = *(const u16x8*)(wqb + (size_t)(w * 16 + q15) * 256 + kb);
      u16x8 wkf = *(const u16x8*)(wqb + (size_t)(128 + w * 16 + q15) * 256 + kb);
      u16x8 wvf = *(const u16x8*)(wqb + (size_t)(256 + w * 16 + q15) * 256 + kb);
#pragma unroll
      for (int t = 0; t < 4; ++t) {
        qa[t] = mfma32(wqf, xb[t], qa[t]);   // Q^T tile: rows=ch, col=tok
        ka[t] = mfma32(wkf, xb[t], ka[t]);   // K^T tile
        va[t] = mfma32(xb[t], wvf, va[t]);   // V tile: rows=tok, col=d
      }
    }
    // stores: C-layout quad (4 rows, fixed col) -> contiguous 8B in [col][row] tiles
#pragma unroll
    for (int t = 0; t < 4; ++t) {
      int tok = t * 16 + q15;
      *(uint2*)(Qs + tok * 256 + ((w * 32 + g * 8) ^ rs)) = pku2(qa[t]);  // Q[tok][ch]
      *(uint2*)(Ks + tok * 256 + ((w * 32 + g * 8) ^ rs)) = pku2(ka[t]);  // K[tok][ch]
      // V^T[d][key]: key-permuted so a 16B read at (s2,g) yields bp8's k-slot order
      *(uint2*)(Vt + (w * 16 + q15) * 128 +
                ((((t >> 1) * 64 + g * 16) + (t & 1) * 8) ^ rs)) = pku2(va[t]);
    }
  }
  __syncthreads();  // B2: Q,K,V visible; xs dead -> reuse as ao

  // ---- attention: wave = (head h, query-half qh); 32 queries ----
  u16x8 kf[4], qf[2];
#pragma unroll
  for (int mk = 0; mk < 4; ++mk)
    kf[mk] = *(const u16x8*)(Ks + (mk * 16 + q15) * 256 + ((h * 64 + g * 16) ^ rs));
#pragma unroll
  for (int nq = 0; nq < 2; ++nq)
    qf[nq] = *(const u16x8*)(Qs + (qh * 32 + nq * 16 + q15) * 256 + ((h * 64 + g * 16) ^ rs));

  f32x4 st[4][2];
#pragma unroll
  for (int mk = 0; mk < 4; ++mk)
#pragma unroll
    for (int nq = 0; nq < 2; ++nq)
      st[mk][nq] = bf4up(bias[mk][nq]);
#pragma unroll
  for (int mk = 0; mk < 4; ++mk)
#pragma unroll
    for (int nq = 0; nq < 2; ++nq)
      st[mk][nq] = mfma32(kf[mk], qf[nq], st[mk][nq]);  // S^T[key][q]

  float rc[2];
#pragma unroll
  for (int nq = 0; nq < 2; ++nq) {
    float s = 0.f;
#pragma unroll
    for (int mk = 0; mk < 4; ++mk)
#pragma unroll
      for (int i = 0; i < 4; ++i) {
        float e = exp2f(st[mk][nq][i]);
        st[mk][nq][i] = e;
        s += e;
      }
    s += __shfl_xor(s, 16);
    s += __shfl_xor(s, 32);
    rc[nq] = __builtin_amdgcn_rcpf(s);
  }
  u16x8 bp8[2][2];
#pragma unroll
  for (int s2 = 0; s2 < 2; ++s2)
#pragma unroll
    for (int nq = 0; nq < 2; ++nq)
      bp8[s2][nq] = pack8(st[2 * s2][nq], st[2 * s2 + 1][nq]);

  // PV: out^T[d][q] += V^T . P^T  (Vt's permuted columns match bp8 k-slots)
  f32x4 ot[2][2];
#pragma unroll
  for (int md = 0; md < 2; ++md)
#pragma unroll
    for (int nq = 0; nq < 2; ++nq) ot[md][nq] = zero4;
#pragma unroll
  for (int s2 = 0; s2 < 2; ++s2) {
    u16x8 vf[2];
#pragma unroll
    for (int md = 0; md < 2; ++md)
      vf[md] = *(const u16x8*)(Vt + (h * 32 + md * 16 + q15) * 128 +
                               ((s2 * 64 + g * 16) ^ rs));
#pragma unroll
    for (int md = 0; md < 2; ++md)
#pragma unroll
      for (int nq = 0; nq < 2; ++nq)
        ot[md][nq] = mfma32(vf[md], bp8[s2][nq], ot[md][nq]);
  }

  // ---- stage normalized attn-out into ao (= xs) ----
  char* ao = xs;
#pragma unroll
  for (int md = 0; md < 2; ++md)
#pragma unroll
    for (int nq = 0; nq < 2; ++nq) {
      int q = qh * 32 + nq * 16 + q15;
      f32x4 v = ot[md][nq];
      uint2 w2;
      w2.x = pk2n(v[0] * rc[nq], v[1] * rc[nq]);
      w2.y = pk2n(v[2] * rc[nq], v[3] * rc[nq]);
      *(uint2*)(ao + q * 256 + ((h * 64 + md * 32 + g * 8) ^ rs)) = w2;
    }

  // ---- prefetch proj weights/bias BEFORE the barrier ----
  u16x8 wpf[4];
#pragma unroll
  for (int ks = 0; ks < 4; ++ks)
    wpf[ks] = *(const u16x8*)(wpb + (size_t)(w * 16 + q15) * 256 + ks * 64 + g * 16);
  f32x4 bv = *(const f32x4*)(bproj + w * 16 + g * 4);
  __syncthreads();  // B3: ao complete

  // ---- proj: wave w owns c_out block w*16; po = Wp^T . ao^T -> [c_out][tok] ----
  f32x4 po[4];
#pragma unroll
  for (int t = 0; t < 4; ++t) po[t] = zero4;
#pragma unroll
  for (int ks = 0; ks < 4; ++ks) {
    u16x8 axb[4];
#pragma unroll
    for (int t = 0; t < 4; ++t)
      axb[t] = *(const u16x8*)(ao + (t * 16 + q15) * 256 + ((ks * 64 + g * 16) ^ rs));
#pragma unroll
    for (int t = 0; t < 4; ++t)
      po[t] = mfma32(wpf[ks], axb[t], po[t]);
  }
  float* op = out + wbase;
#pragma unroll
  for (int t = 0; t < 4; ++t) {
    f32x4 vs = po[t] + bv;
    *(f32x4*)(op + (size_t)(t * 16 + q15) * 128 + w * 16 + g * 4) = vs;
  }
}

extern "C" void kernel_launch(void* const* d_in, const int* in_sizes, int n_in,
                              void* d_out, int out_size, void* d_ws, size_t ws_size,
                              hipStream_t stream) {
  const float* x     = (const float*)d_in[0];
  const float* wqkv  = (const float*)d_in[1];
  const float* wproj = (const float*)d_in[2];
  const float* bproj = (const float*)d_in[3];
  const float* btab  = (const float*)d_in[4];
  char* ws = (char*)d_ws;
  unsigned short* wqkvt  = (unsigned short*)ws;             // 98304 B
  unsigned short* wprojt = (unsigned short*)(ws + 98304);   // 32768 B
  unsigned short* biasbf = (unsigned short*)(ws + 131072);  // 32768 B

  prep_kernel<<<320, 256, 0, stream>>>(wqkv, wproj, btab, wqkvt, wprojt, biasbf);
  attn_kernel<<<4096, 512, 0, stream>>>(x, wqkvt, wprojt, biasbf, bproj, (float*)d_out);
}